// Round 1
// baseline (751.474 us; speedup 1.0000x reference)
//
#include <hip/hip_runtime.h>
#include <hip/hip_bf16.h>

// Problem constants
#define B_   8
#define N_   128
#define HW_  16384
#define C_   768
#define NIN_ 1545
#define NINP_ 1600   // padded K for layer-1 GEMM (multiple of 64)
#define D1_  512
#define D_   256
#define EO_  128
#define KC_  16      // split-K factor for pooled_k

typedef short s16x8 __attribute__((ext_vector_type(8)));
typedef float f32x16 __attribute__((ext_vector_type(16)));

__device__ __forceinline__ unsigned short f2bf(float x) {
  union { __hip_bfloat16 h; unsigned short u; } cv;
  cv.h = __float2bfloat16(x);
  return cv.u;
}

// ---------------- kernel 1: fused mask stats + weight conversion ------------
// blocks [0,1024): mask stats (sum, centroid -> motion)
// blocks [1024,5376): weight f32->bf16 conversion (hidden under masks read)
__global__ __launch_bounds__(256) void prep_k(const float* __restrict__ masks,
                                              const float* __restrict__ depth,
                                              const float* __restrict__ pose,
                                              float4* __restrict__ stats,
                                              const float* __restrict__ w1,
                                              const float* __restrict__ w2,
                                              const float* __restrict__ ew1,
                                              const float* __restrict__ ew2,
                                              unsigned short* __restrict__ w1b,
                                              unsigned short* __restrict__ w2b,
                                              unsigned short* __restrict__ we1b,
                                              unsigned short* __restrict__ ew2b) {
  if (blockIdx.x >= 1024) {
    int i = (blockIdx.x - 1024) * 256 + threadIdx.x;
    if (i < 512 * NINP_) {                       // node_w1 -> 512 x 1600 (pad 0)
      int r = i / NINP_, k = i - r * NINP_;
      w1b[i] = f2bf(k < NIN_ ? w1[r * NIN_ + k] : 0.0f);
      return;
    }
    i -= 512 * NINP_;
    if (i < 256 * 512) { w2b[i] = f2bf(w2[i]); return; }   // node_w2 256x512
    i -= 256 * 512;
    if (i < 512 * 256) {                         // [w1a; w1b] rows: 512 x 256
      int r = i >> 8, k = i & 255;
      we1b[i] = f2bf(r < 256 ? ew1[r * 512 + k] : ew1[(r - 256) * 512 + 256 + k]);
      return;
    }
    i -= 512 * 256;
    if (i < 128 * 256) { ew2b[i] = f2bf(ew2[i]); }          // edge_w2 128x256
    return;
  }
  int row = blockIdx.x;            // b*128 + n
  int b = row >> 7;
  const float4* mp = (const float4*)(masks + (size_t)row * HW_);
  double s = 0.0, sx = 0.0, sy = 0.0;
  for (int it = 0; it < 16; ++it) {
    int i4 = threadIdx.x + it * 256;
    float4 v = mp[i4];
    int flat = i4 * 4;
    int y = flat >> 7, xb = flat & 127;
    double rs = (double)v.x + (double)v.y + (double)v.z + (double)v.w;
    s += rs;
    sx += (double)v.x * xb + (double)v.y * (xb + 1) + (double)v.z * (xb + 2) + (double)v.w * (xb + 3);
    sy += rs * (double)y;
  }
  for (int off = 32; off; off >>= 1) {
    s  += __shfl_down(s,  off);
    sx += __shfl_down(sx, off);
    sy += __shfl_down(sy, off);
  }
  __shared__ double red[3][4];
  int w = threadIdx.x >> 6, l = threadIdx.x & 63;
  if (l == 0) { red[0][w] = s; red[1][w] = sx; red[2][w] = sy; }
  __syncthreads();
  if (threadIdx.x == 0) {
    s  = red[0][0] + red[0][1] + red[0][2] + red[0][3];
    sx = red[1][0] + red[1][1] + red[1][2] + red[1][3];
    sy = red[2][0] + red[2][1] + red[2][2] + red[2][3];
    double msum = s + 1e-6;
    double cx = sx / msum, cy = sy / msum;
    int cxi = (int)rint(cx); cxi = min(127, max(0, cxi));
    int cyi = (int)rint(cy); cyi = min(127, max(0, cyi));
    double z = (double)depth[(size_t)b * HW_ + cyi * 128 + cxi];
    // K = I3: X = cx*z, Y = cy*z
    double Ph[4] = { cx * z, cy * z, z, 1.0 };
    const float* P = pose + b * 16;
    double pn[4];
    #pragma unroll
    for (int r = 0; r < 4; ++r)
      pn[r] = (double)P[r*4+0]*Ph[0] + (double)P[r*4+1]*Ph[1] + (double)P[r*4+2]*Ph[2] + (double)P[r*4+3]*Ph[3];
    double inv3 = 1.0 / pn[3];
    stats[row] = make_float4((float)(1.0 / msum), (float)(pn[0]*inv3), (float)(pn[1]*inv3), (float)(pn[2]*inv3));
  }
}

// ---------------- kernel 2: pooled = masks @ feats^T (split-K, bf16 MFMA) ---
// grid (96, 8): logical x = kc*6 + ct (kc in [0,16)), y = b.
// XCD-grouping swizzle: the 6 ct-siblings sharing one masks chunk land on the
// SAME XCD L2 (default round-robin spreads them over 6 XCDs -> 6x LLC traffic).
// Register double-buffer: issue kt+1's 16 float4 loads before kt's MFMA.
__global__ __launch_bounds__(256) void pooled_k(const float* __restrict__ masks,
                                                const float* __restrict__ feats,
                                                float* __restrict__ Spart) {
  __shared__ short As[128 * 72];
  __shared__ short Bs[128 * 72];
  int id = blockIdx.x + 96 * blockIdx.y;        // hw id, 0..767
  int lg = (id & 7) * 96 + (id >> 3);           // bijective: 768 % 8 == 0
  int b  = lg / 96;
  int lx = lg - b * 96;
  int ct = lx % 6, kc = lx / 6;                 // kc in [0,16): K-chunk of 1024
  const float* mb = masks + (size_t)b * N_ * HW_;
  const float* fb = feats + ((size_t)b * C_ + (size_t)ct * 128) * HW_;
  int t = threadIdx.x, w = t >> 6, l = t & 63;
  int rsel = l & 31, khalf = l >> 5;
  f32x16 acc[4];
  #pragma unroll
  for (int nt = 0; nt < 4; ++nt)
    #pragma unroll
    for (int i = 0; i < 16; ++i) acc[nt][i] = 0.0f;

  float4 va[8], vb[8];
  auto issue = [&](int kt) {
    int kbase = kc * 1024 + kt * 64;
    #pragma unroll
    for (int c = 0; c < 8; ++c) {
      int chunk = t + 256 * c;           // 0..2047
      int row = chunk >> 4;              // 0..127
      int kof = (chunk & 15) << 2;       // 0..60
      va[c] = *(const float4*)(mb + (size_t)row * HW_ + kbase + kof);
      vb[c] = *(const float4*)(fb + (size_t)row * HW_ + kbase + kof);
    }
  };
  issue(0);
  for (int kt = 0; kt < 16; ++kt) {
    #pragma unroll
    for (int c = 0; c < 8; ++c) {
      int chunk = t + 256 * c;
      int row = chunk >> 4;
      int kof = (chunk & 15) << 2;
      float4 A4 = va[c], B4 = vb[c];
      ushort4 pa = { f2bf(A4.x), f2bf(A4.y), f2bf(A4.z), f2bf(A4.w) };
      *(ushort4*)((unsigned short*)As + row * 72 + kof) = pa;
      ushort4 pb = { f2bf(B4.x), f2bf(B4.y), f2bf(B4.z), f2bf(B4.w) };
      *(ushort4*)((unsigned short*)Bs + row * 72 + kof) = pb;
    }
    if (kt < 15) issue(kt + 1);          // in flight across MFMA phase
    __syncthreads();
    #pragma unroll
    for (int ks = 0; ks < 4; ++ks) {
      s16x8 a = *(const s16x8*)&As[(w * 32 + rsel) * 72 + ks * 16 + khalf * 8];
      #pragma unroll
      for (int nt = 0; nt < 4; ++nt) {
        s16x8 bf = *(const s16x8*)&Bs[(nt * 32 + rsel) * 72 + ks * 16 + khalf * 8];
        acc[nt] = __builtin_amdgcn_mfma_f32_32x32x16_bf16(a, bf, acc[nt], 0, 0, 0);
      }
    }
    __syncthreads();
  }
  float* op = Spart + (size_t)kc * 786432 + (size_t)b * 98304;
  #pragma unroll
  for (int nt = 0; nt < 4; ++nt)
    #pragma unroll
    for (int reg = 0; reg < 16; ++reg) {
      int rm = w * 32 + (reg & 3) + 8 * (reg >> 2) + 4 * khalf;
      int cn = ct * 128 + nt * 32 + rsel;
      op[rm * C_ + cn] = acc[nt][reg];
    }
}

// ---------------- kernel 3a: reduce split-K partials + assemble node_input --
__global__ __launch_bounds__(256) void assemble_k(const float* __restrict__ Spart,
                                                  const float4* __restrict__ stats,
                                                  const float* __restrict__ obj,
                                                  const float* __restrict__ bboxes,
                                                  const float* __restrict__ conf,
                                                  unsigned short* __restrict__ ni) {
  int r = blockIdx.x;
  float4 st = stats[r];
  float x1 = bboxes[r*4+0], y1 = bboxes[r*4+1], x2 = bboxes[r*4+2], y2 = bboxes[r*4+3];
  for (int k = threadIdx.x; k < NINP_; k += 256) {
    float v;
    if (k < 768) {
      float acc = 0.0f;
      #pragma unroll
      for (int kc = 0; kc < KC_; ++kc) acc += Spart[(size_t)kc * 786432 + (size_t)r * C_ + k];
      v = acc * st.x;
    } else if (k < 1537) v = obj[(size_t)r * 769 + (k - 768)];
    else if (k == 1537) v = 0.5f * (x1 + x2);
    else if (k == 1538) v = 0.5f * (y1 + y2);
    else if (k == 1539) v = x2 - x1;
    else if (k == 1540) v = y2 - y1;
    else if (k == 1541) v = conf[r];
    else if (k == 1542) v = st.y;
    else if (k == 1543) v = st.z;
    else if (k == 1544) v = st.w;
    else v = 0.0f;
    ni[(size_t)r * NINP_ + k] = f2bf(v);
  }
}

// ---------------- generic 64x64 bf16 GEMM: C[m,n] = act(bias + A·B^T) -------
// A: M x K bf16 (row-major, stride K), B: N x K bf16. K multiple of 64.
template <bool RELU, bool BIAS, int OUTM>  // OUTM: 0 f32, 1 bf16, 2 both
__global__ __launch_bounds__(256) void gemm64_k(const unsigned short* __restrict__ A,
                                                const unsigned short* __restrict__ Bm,
                                                const float* __restrict__ bias,
                                                float* __restrict__ Cf,
                                                unsigned short* __restrict__ Cb,
                                                int K, int N) {
  __shared__ short As[64 * 72];
  __shared__ short Bs[64 * 72];
  int n0 = blockIdx.x * 64, m0 = blockIdx.y * 64;
  int t = threadIdx.x, w = t >> 6, l = t & 63;
  int rsel = l & 31, khalf = l >> 5;
  int mh = (w & 1) * 32, nh = (w >> 1) * 32;
  f32x16 acc;
  #pragma unroll
  for (int i = 0; i < 16; ++i) acc[i] = 0.0f;

  for (int k0 = 0; k0 < K; k0 += 64) {
    #pragma unroll
    for (int c = 0; c < 2; ++c) {
      int chunk = t + 256 * c;            // 0..511
      int row = chunk >> 3, kof = (chunk & 7) * 8;
      *(uint4*)((unsigned short*)As + row * 72 + kof) =
          *(const uint4*)&A[(size_t)(m0 + row) * K + k0 + kof];
      *(uint4*)((unsigned short*)Bs + row * 72 + kof) =
          *(const uint4*)&Bm[(size_t)(n0 + row) * K + k0 + kof];
    }
    __syncthreads();
    #pragma unroll
    for (int ks = 0; ks < 4; ++ks) {
      s16x8 a = *(const s16x8*)&As[(mh + rsel) * 72 + ks * 16 + khalf * 8];
      s16x8 bf = *(const s16x8*)&Bs[(nh + rsel) * 72 + ks * 16 + khalf * 8];
      acc = __builtin_amdgcn_mfma_f32_32x32x16_bf16(a, bf, acc, 0, 0, 0);
    }
    __syncthreads();
  }
  #pragma unroll
  for (int reg = 0; reg < 16; ++reg) {
    int rm = m0 + mh + (reg & 3) + 8 * (reg >> 2) + 4 * khalf;
    int cn = n0 + nh + rsel;
    float v = acc[reg];
    if (BIAS) v += bias[cn];
    if (RELU) v = fmaxf(v, 0.0f);
    if (OUTM == 0 || OUTM == 2) Cf[(size_t)rm * N + cn] = v;
    if (OUTM == 1 || OUTM == 2) Cb[(size_t)rm * N + cn] = f2bf(v);
  }
}

// ---------------- kernel 4: fused edge MLP + adjacency ----------------------
// grid 2048 with XCD-grouping swizzle; lg < 1024: edge MLP for (b,i),
// lg >= 1024: adjacency row (b,i) via coalesced LDS-tiled dot products.
__global__ __launch_bounds__(256) void edge_adj_k(const float* __restrict__ hihj,
                                                  const unsigned short* __restrict__ ew2b,
                                                  const float* __restrict__ eb1,
                                                  const float* __restrict__ eb2,
                                                  const float* __restrict__ ne,
                                                  float* __restrict__ out_edge,
                                                  float* __restrict__ out_adj) {
  __shared__ union {
    struct { short W2s[128 * 264]; float hi_s[256]; float b1_s[256]; float b2_s[128]; } e;
    struct { float njs[128 * 65]; float nei[256]; float red[3][256]; } a;
  } sm;
  int id = blockIdx.x;                    // 0..2047
  int lg = (id & 7) * 256 + (id >> 3);    // bijective: 2048 % 8 == 0
  int t = threadIdx.x;

  if (lg < 1024) {
    // ---- edge MLP: he[j,k]=relu(hi[i,k]+hj[j,k]+b1[k]) in-reg, GEMM vs w2 --
    int bi = lg;                          // b*128 + i
    int b = bi >> 7;
    int w = t >> 6, l = t & 63;
    int rsel = l & 31, khalf = l >> 5;

    #pragma unroll
    for (int c = 0; c < 16; ++c) {
      int chunk = t + 256 * c;            // 0..4095
      int row = chunk >> 5, kof = (chunk & 31) * 8;
      *(uint4*)((unsigned short*)sm.e.W2s + row * 264 + kof) = *(const uint4*)&ew2b[row * 256 + kof];
    }
    sm.e.hi_s[t] = hihj[(size_t)bi * 512 + t];    // hi of node i
    sm.e.b1_s[t] = eb1[t];
    if (t < 128) sm.e.b2_s[t] = eb2[t];
    __syncthreads();

    f32x16 acc[4];
    #pragma unroll
    for (int nt = 0; nt < 4; ++nt)
      #pragma unroll
      for (int i = 0; i < 16; ++i) acc[nt][i] = 0.0f;

    const float* hjb = hihj + (size_t)b * 128 * 512 + 256;
    int jrow = w * 32 + rsel;
    #pragma unroll
    for (int ks = 0; ks < 16; ++ks) {
      int k0 = ks * 16 + khalf * 8;
      const float* hp = hjb + (size_t)jrow * 512 + k0;
      float4 h0 = *(const float4*)hp;
      float4 h1 = *(const float4*)(hp + 4);
      float f[8] = { h0.x, h0.y, h0.z, h0.w, h1.x, h1.y, h1.z, h1.w };
      s16x8 a;
      #pragma unroll
      for (int c = 0; c < 8; ++c)
        a[c] = (short)f2bf(fmaxf(f[c] + sm.e.hi_s[k0 + c] + sm.e.b1_s[k0 + c], 0.0f));
      #pragma unroll
      for (int nt = 0; nt < 4; ++nt) {
        s16x8 bf = *(const s16x8*)&sm.e.W2s[(nt * 32 + rsel) * 264 + k0];
        acc[nt] = __builtin_amdgcn_mfma_f32_32x32x16_bf16(a, bf, acc[nt], 0, 0, 0);
      }
    }
    float* ob = out_edge + (size_t)bi * 128 * 128;
    #pragma unroll
    for (int nt = 0; nt < 4; ++nt)
      #pragma unroll
      for (int reg = 0; reg < 16; ++reg) {
        int j = w * 32 + (reg & 3) + 8 * (reg >> 2) + 4 * khalf;
        int o = nt * 32 + rsel;
        ob[(size_t)j * 128 + o] = acc[nt][reg] + sm.e.b2_s[o];
      }
  } else {
    // ---- adjacency: row i of exp(-||ne_i - ne_j||) via LDS-tiled dots ------
    int bi = lg - 1024;                   // b*128 + i
    int b = bi >> 7;
    const float* neb = ne + (size_t)b * 128 * 256;
    int j = t & 127, kh = t >> 7;
    sm.a.nei[t] = ne[(size_t)bi * 256 + t];
    float dot = 0.0f, sqj = 0.0f, sqi = 0.0f;
    for (int tile = 0; tile < 4; ++tile) {
      __syncthreads();
      #pragma unroll
      for (int p = 0; p < 8; ++p) {
        int f = p * 256 + t;              // 0..2047 float4s
        int row = f >> 4;                 // 0..127
        int k4 = (f & 15) << 2;           // 0..60
        float4 v = *(const float4*)(neb + (size_t)row * 256 + tile * 64 + k4);
        float* dst = &sm.a.njs[row * 65 + k4];
        dst[0] = v.x; dst[1] = v.y; dst[2] = v.z; dst[3] = v.w;
      }
      __syncthreads();
      int kb = tile * 64 + kh * 32;
      #pragma unroll
      for (int k = 0; k < 32; ++k) {
        float c = sm.a.njs[j * 65 + kh * 32 + k];
        float aa = sm.a.nei[kb + k];
        dot += aa * c; sqj += c * c; sqi += aa * aa;
      }
    }
    __syncthreads();
    sm.a.red[0][t] = dot; sm.a.red[1][t] = sqj; sm.a.red[2][t] = sqi;
    __syncthreads();
    if (t < 128) {
      dot = sm.a.red[0][t] + sm.a.red[0][t + 128];
      sqj = sm.a.red[1][t] + sm.a.red[1][t + 128];
      sqi = sm.a.red[2][t] + sm.a.red[2][t + 128];
      float d2 = fmaxf(sqi + sqj - 2.0f * dot, 0.0f);
      float d = d2 > 0.0f ? sqrtf(d2) : 0.0f;
      out_adj[(size_t)bi * 128 + t] = expf(-d);
    }
  }
}

// ---------------- launch -----------------------------------------------------
extern "C" void kernel_launch(void* const* d_in, const int* in_sizes, int n_in,
                              void* d_out, int out_size, void* d_ws, size_t ws_size,
                              hipStream_t stream) {
  const float* obj    = (const float*)d_in[0];
  const float* masks  = (const float*)d_in[1];
  const float* feats  = (const float*)d_in[2];
  const float* bboxes = (const float*)d_in[3];
  const float* conf   = (const float*)d_in[4];
  const float* depth  = (const float*)d_in[5];
  const float* pose   = (const float*)d_in[6];
  const float* nw1    = (const float*)d_in[7];
  const float* nb1    = (const float*)d_in[8];
  const float* nw2    = (const float*)d_in[9];
  const float* nb2    = (const float*)d_in[10];
  const float* ew1    = (const float*)d_in[11];
  const float* eb1    = (const float*)d_in[12];
  const float* ew2    = (const float*)d_in[13];
  const float* eb2    = (const float*)d_in[14];

  char* ws = (char*)d_ws;
  // Spart: 16 * 786432 f32 = 50331648 B. h_bf / ne_bf / hihj are carved out of
  // the Spart region (Spart is dead after assemble_k runs).
  float*          Spart = (float*)ws;
  unsigned short* h_bf  = (unsigned short*)ws;                    // 1024x512 bf16 = 1 MiB
  unsigned short* ne_bf = (unsigned short*)(ws + 1048576);        // 1024x256 bf16 = 512 KiB
  float*          hihj  = (float*)(ws + 1572864);                 // 1024x512 f32 = 2 MiB
  float4*         stats = (float4*)(ws + 50331648);               // 16 KiB
  unsigned short* ni_bf = (unsigned short*)(ws + 50348032);       // 1024x1600 bf16
  unsigned short* w1b   = (unsigned short*)(ws + 53624832);       // 512x1600 bf16
  unsigned short* w2b   = (unsigned short*)(ws + 55263232);       // 256x512 bf16
  unsigned short* we1b  = (unsigned short*)(ws + 55525376);       // 512x256 bf16
  unsigned short* ew2b  = (unsigned short*)(ws + 55787520);       // 128x256 bf16
  // total used: 55853056 B (~53.3 MiB)

  float* out      = (float*)d_out;
  float* out_ne   = out;                         // 8*128*256
  float* out_edge = out + 262144;                // 8*128*128*128
  float* out_adj  = out + 262144 + 16777216;     // 8*128*128

  prep_k<<<dim3(5376), dim3(256), 0, stream>>>(masks, depth, pose, stats,
                                               nw1, nw2, ew1, ew2, w1b, w2b, we1b, ew2b);
  pooled_k<<<dim3(96, 8), dim3(256), 0, stream>>>(masks, feats, Spart);
  assemble_k<<<dim3(1024), dim3(256), 0, stream>>>(Spart, stats, obj, bboxes, conf, ni_bf);
  gemm64_k<true,  true,  1><<<dim3(8, 16), dim3(256), 0, stream>>>(ni_bf, w1b, nb1, nullptr, h_bf, NINP_, 512);
  gemm64_k<false, true,  2><<<dim3(4, 16), dim3(256), 0, stream>>>(h_bf, w2b, nb2, out_ne, ne_bf, 512, 256);
  gemm64_k<false, false, 0><<<dim3(8, 16), dim3(256), 0, stream>>>(ne_bf, we1b, nullptr, hihj, nullptr, 256, 512);
  edge_adj_k<<<dim3(2048), dim3(256), 0, stream>>>(hihj, ew2b, eb1, eb2, out_ne, out_edge, out_adj);
}

// Round 3
// 738.060 us; speedup vs baseline: 1.0182x; 1.0182x over previous
//
#include <hip/hip_runtime.h>
#include <hip/hip_bf16.h>

// Problem constants
#define B_   8
#define N_   128
#define HW_  16384
#define C_   768
#define NIN_ 1545
#define NINP_ 1600   // padded K for layer-1 GEMM (multiple of 64)
#define D1_  512
#define D_   256
#define EO_  128
#define KC_  16      // split-K factor for pooled_k

typedef short s16x8 __attribute__((ext_vector_type(8)));
typedef float f32x16 __attribute__((ext_vector_type(16)));

__device__ __forceinline__ unsigned short f2bf(float x) {
  union { __hip_bfloat16 h; unsigned short u; } cv;
  cv.h = __float2bfloat16(x);
  return cv.u;
}

// ---------------- kernel 1: fused mask stats + weight conversion ------------
// blocks [0,1024): mask stats (sum, centroid -> motion)
// blocks [1024,5376): weight f32->bf16 conversion (hidden under masks read)
__global__ __launch_bounds__(256) void prep_k(const float* __restrict__ masks,
                                              const float* __restrict__ depth,
                                              const float* __restrict__ pose,
                                              float4* __restrict__ stats,
                                              const float* __restrict__ w1,
                                              const float* __restrict__ w2,
                                              const float* __restrict__ ew1,
                                              const float* __restrict__ ew2,
                                              unsigned short* __restrict__ w1b,
                                              unsigned short* __restrict__ w2b,
                                              unsigned short* __restrict__ we1b,
                                              unsigned short* __restrict__ ew2b) {
  if (blockIdx.x >= 1024) {
    int i = (blockIdx.x - 1024) * 256 + threadIdx.x;
    if (i < 512 * NINP_) {                       // node_w1 -> 512 x 1600 (pad 0)
      int r = i / NINP_, k = i - r * NINP_;
      w1b[i] = f2bf(k < NIN_ ? w1[r * NIN_ + k] : 0.0f);
      return;
    }
    i -= 512 * NINP_;
    if (i < 256 * 512) { w2b[i] = f2bf(w2[i]); return; }   // node_w2 256x512
    i -= 256 * 512;
    if (i < 512 * 256) {                         // [w1a; w1b] rows: 512 x 256
      int r = i >> 8, k = i & 255;
      we1b[i] = f2bf(r < 256 ? ew1[r * 512 + k] : ew1[(r - 256) * 512 + 256 + k]);
      return;
    }
    i -= 512 * 256;
    if (i < 128 * 256) { ew2b[i] = f2bf(ew2[i]); }          // edge_w2 128x256
    return;
  }
  int row = blockIdx.x;            // b*128 + n
  int b = row >> 7;
  const float4* mp = (const float4*)(masks + (size_t)row * HW_);
  double s = 0.0, sx = 0.0, sy = 0.0;
  for (int it = 0; it < 16; ++it) {
    int i4 = threadIdx.x + it * 256;
    float4 v = mp[i4];
    int flat = i4 * 4;
    int y = flat >> 7, xb = flat & 127;
    double rs = (double)v.x + (double)v.y + (double)v.z + (double)v.w;
    s += rs;
    sx += (double)v.x * xb + (double)v.y * (xb + 1) + (double)v.z * (xb + 2) + (double)v.w * (xb + 3);
    sy += rs * (double)y;
  }
  for (int off = 32; off; off >>= 1) {
    s  += __shfl_down(s,  off);
    sx += __shfl_down(sx, off);
    sy += __shfl_down(sy, off);
  }
  __shared__ double red[3][4];
  int w = threadIdx.x >> 6, l = threadIdx.x & 63;
  if (l == 0) { red[0][w] = s; red[1][w] = sx; red[2][w] = sy; }
  __syncthreads();
  if (threadIdx.x == 0) {
    s  = red[0][0] + red[0][1] + red[0][2] + red[0][3];
    sx = red[1][0] + red[1][1] + red[1][2] + red[1][3];
    sy = red[2][0] + red[2][1] + red[2][2] + red[2][3];
    double msum = s + 1e-6;
    double cx = sx / msum, cy = sy / msum;
    int cxi = (int)rint(cx); cxi = min(127, max(0, cxi));
    int cyi = (int)rint(cy); cyi = min(127, max(0, cyi));
    double z = (double)depth[(size_t)b * HW_ + cyi * 128 + cxi];
    // K = I3: X = cx*z, Y = cy*z
    double Ph[4] = { cx * z, cy * z, z, 1.0 };
    const float* P = pose + b * 16;
    double pn[4];
    #pragma unroll
    for (int r = 0; r < 4; ++r)
      pn[r] = (double)P[r*4+0]*Ph[0] + (double)P[r*4+1]*Ph[1] + (double)P[r*4+2]*Ph[2] + (double)P[r*4+3]*Ph[3];
    double inv3 = 1.0 / pn[3];
    stats[row] = make_float4((float)(1.0 / msum), (float)(pn[0]*inv3), (float)(pn[1]*inv3), (float)(pn[2]*inv3));
  }
}

// ---------------- kernel 2: pooled = masks @ feats^T (split-K, bf16 MFMA) ---
// grid (96, 8): logical x = kc*6 + ct (kc in [0,16)), y = b.
// XCD-grouping swizzle: the 6 ct-siblings sharing one masks chunk land on the
// SAME XCD L2. Plain load->cvt->LDS staging (no reg dbuf: VGPR pressure halves
// occupancy and this kernel is HBM-bound -> needs waves, not ILP).
__global__ __launch_bounds__(256) void pooled_k(const float* __restrict__ masks,
                                                const float* __restrict__ feats,
                                                float* __restrict__ Spart) {
  __shared__ short As[128 * 72];
  __shared__ short Bs[128 * 72];
  int id = blockIdx.x + 96 * blockIdx.y;        // hw id, 0..767
  int lg = (id & 7) * 96 + (id >> 3);           // bijective: 768 % 8 == 0
  int b  = lg / 96;
  int lx = lg - b * 96;
  int ct = lx % 6, kc = lx / 6;                 // kc in [0,16): K-chunk of 1024
  const float* mb = masks + (size_t)b * N_ * HW_;
  const float* fb = feats + ((size_t)b * C_ + (size_t)ct * 128) * HW_;
  int t = threadIdx.x, w = t >> 6, l = t & 63;
  int rsel = l & 31, khalf = l >> 5;
  f32x16 acc[4];
  #pragma unroll
  for (int nt = 0; nt < 4; ++nt)
    #pragma unroll
    for (int i = 0; i < 16; ++i) acc[nt][i] = 0.0f;

  for (int kt = 0; kt < 16; ++kt) {
    int kbase = kc * 1024 + kt * 64;
    #pragma unroll
    for (int c = 0; c < 8; ++c) {
      int chunk = t + 256 * c;           // 0..2047
      int row = chunk >> 4;              // 0..127
      int kof = (chunk & 15) << 2;       // 0..60
      float4 va = *(const float4*)(mb + (size_t)row * HW_ + kbase + kof);
      ushort4 pa = { f2bf(va.x), f2bf(va.y), f2bf(va.z), f2bf(va.w) };
      *(ushort4*)((unsigned short*)As + row * 72 + kof) = pa;
      float4 vb = *(const float4*)(fb + (size_t)row * HW_ + kbase + kof);
      ushort4 pb = { f2bf(vb.x), f2bf(vb.y), f2bf(vb.z), f2bf(vb.w) };
      *(ushort4*)((unsigned short*)Bs + row * 72 + kof) = pb;
    }
    __syncthreads();
    #pragma unroll
    for (int ks = 0; ks < 4; ++ks) {
      s16x8 a = *(const s16x8*)&As[(w * 32 + rsel) * 72 + ks * 16 + khalf * 8];
      #pragma unroll
      for (int nt = 0; nt < 4; ++nt) {
        s16x8 bf = *(const s16x8*)&Bs[(nt * 32 + rsel) * 72 + ks * 16 + khalf * 8];
        acc[nt] = __builtin_amdgcn_mfma_f32_32x32x16_bf16(a, bf, acc[nt], 0, 0, 0);
      }
    }
    __syncthreads();
  }
  float* op = Spart + (size_t)kc * 786432 + (size_t)b * 98304;
  #pragma unroll
  for (int nt = 0; nt < 4; ++nt)
    #pragma unroll
    for (int reg = 0; reg < 16; ++reg) {
      int rm = w * 32 + (reg & 3) + 8 * (reg >> 2) + 4 * khalf;
      int cn = ct * 128 + nt * 32 + rsel;
      op[rm * C_ + cn] = acc[nt][reg];
    }
}

// ---------------- kernel 3a: reduce split-K partials + assemble node_input --
__global__ __launch_bounds__(256) void assemble_k(const float* __restrict__ Spart,
                                                  const float4* __restrict__ stats,
                                                  const float* __restrict__ obj,
                                                  const float* __restrict__ bboxes,
                                                  const float* __restrict__ conf,
                                                  unsigned short* __restrict__ ni) {
  int r = blockIdx.x;
  float4 st = stats[r];
  float x1 = bboxes[r*4+0], y1 = bboxes[r*4+1], x2 = bboxes[r*4+2], y2 = bboxes[r*4+3];
  for (int k = threadIdx.x; k < NINP_; k += 256) {
    float v;
    if (k < 768) {
      float acc = 0.0f;
      #pragma unroll
      for (int kc = 0; kc < KC_; ++kc) acc += Spart[(size_t)kc * 786432 + (size_t)r * C_ + k];
      v = acc * st.x;
    } else if (k < 1537) v = obj[(size_t)r * 769 + (k - 768)];
    else if (k == 1537) v = 0.5f * (x1 + x2);
    else if (k == 1538) v = 0.5f * (y1 + y2);
    else if (k == 1539) v = x2 - x1;
    else if (k == 1540) v = y2 - y1;
    else if (k == 1541) v = conf[r];
    else if (k == 1542) v = st.y;
    else if (k == 1543) v = st.z;
    else if (k == 1544) v = st.w;
    else v = 0.0f;
    ni[(size_t)r * NINP_ + k] = f2bf(v);
  }
}

// ---------------- generic 64x64 bf16 GEMM: C[m,n] = act(bias + A·B^T) -------
// A: M x K bf16 (row-major, stride K), B: N x K bf16. K multiple of 64.
template <bool RELU, bool BIAS, int OUTM>  // OUTM: 0 f32, 1 bf16, 2 both
__global__ __launch_bounds__(256) void gemm64_k(const unsigned short* __restrict__ A,
                                                const unsigned short* __restrict__ Bm,
                                                const float* __restrict__ bias,
                                                float* __restrict__ Cf,
                                                unsigned short* __restrict__ Cb,
                                                int K, int N) {
  __shared__ short As[64 * 72];
  __shared__ short Bs[64 * 72];
  int n0 = blockIdx.x * 64, m0 = blockIdx.y * 64;
  int t = threadIdx.x, w = t >> 6, l = t & 63;
  int rsel = l & 31, khalf = l >> 5;
  int mh = (w & 1) * 32, nh = (w >> 1) * 32;
  f32x16 acc;
  #pragma unroll
  for (int i = 0; i < 16; ++i) acc[i] = 0.0f;

  for (int k0 = 0; k0 < K; k0 += 64) {
    #pragma unroll
    for (int c = 0; c < 2; ++c) {
      int chunk = t + 256 * c;            // 0..511
      int row = chunk >> 3, kof = (chunk & 7) * 8;
      *(uint4*)((unsigned short*)As + row * 72 + kof) =
          *(const uint4*)&A[(size_t)(m0 + row) * K + k0 + kof];
      *(uint4*)((unsigned short*)Bs + row * 72 + kof) =
          *(const uint4*)&Bm[(size_t)(n0 + row) * K + k0 + kof];
    }
    __syncthreads();
    #pragma unroll
    for (int ks = 0; ks < 4; ++ks) {
      s16x8 a = *(const s16x8*)&As[(mh + rsel) * 72 + ks * 16 + khalf * 8];
      s16x8 bf = *(const s16x8*)&Bs[(nh + rsel) * 72 + ks * 16 + khalf * 8];
      acc = __builtin_amdgcn_mfma_f32_32x32x16_bf16(a, bf, acc, 0, 0, 0);
    }
    __syncthreads();
  }
  #pragma unroll
  for (int reg = 0; reg < 16; ++reg) {
    int rm = m0 + mh + (reg & 3) + 8 * (reg >> 2) + 4 * khalf;
    int cn = n0 + nh + rsel;
    float v = acc[reg];
    if (BIAS) v += bias[cn];
    if (RELU) v = fmaxf(v, 0.0f);
    if (OUTM == 0 || OUTM == 2) Cf[(size_t)rm * N + cn] = v;
    if (OUTM == 1 || OUTM == 2) Cb[(size_t)rm * N + cn] = f2bf(v);
  }
}

// ---------------- kernel 4: fused edge MLP + adjacency ----------------------
// grid 2048 with XCD-grouping swizzle; lg < 1024: edge MLP for (b,i),
// lg >= 1024: adjacency row (b,i) via coalesced LDS-tiled dot products.
__global__ __launch_bounds__(256) void edge_adj_k(const float* __restrict__ hihj,
                                                  const unsigned short* __restrict__ ew2b,
                                                  const float* __restrict__ eb1,
                                                  const float* __restrict__ eb2,
                                                  const float* __restrict__ ne,
                                                  float* __restrict__ out_edge,
                                                  float* __restrict__ out_adj) {
  __shared__ union {
    struct { short W2s[128 * 264]; float hi_s[256]; float b1_s[256]; float b2_s[128]; } e;
    struct { float njs[128 * 65]; float nei[256]; float red[3][256]; } a;
  } sm;
  int id = blockIdx.x;                    // 0..2047
  int lg = (id & 7) * 256 + (id >> 3);    // bijective: 2048 % 8 == 0
  int t = threadIdx.x;

  if (lg < 1024) {
    // ---- edge MLP: he[j,k]=relu(hi[i,k]+hj[j,k]+b1[k]) in-reg, GEMM vs w2 --
    int bi = lg;                          // b*128 + i
    int b = bi >> 7;
    int w = t >> 6, l = t & 63;
    int rsel = l & 31, khalf = l >> 5;

    #pragma unroll
    for (int c = 0; c < 16; ++c) {
      int chunk = t + 256 * c;            // 0..4095
      int row = chunk >> 5, kof = (chunk & 31) * 8;
      *(uint4*)((unsigned short*)sm.e.W2s + row * 264 + kof) = *(const uint4*)&ew2b[row * 256 + kof];
    }
    sm.e.hi_s[t] = hihj[(size_t)bi * 512 + t];    // hi of node i
    sm.e.b1_s[t] = eb1[t];
    if (t < 128) sm.e.b2_s[t] = eb2[t];
    __syncthreads();

    f32x16 acc[4];
    #pragma unroll
    for (int nt = 0; nt < 4; ++nt)
      #pragma unroll
      for (int i = 0; i < 16; ++i) acc[nt][i] = 0.0f;

    const float* hjb = hihj + (size_t)b * 128 * 512 + 256;
    int jrow = w * 32 + rsel;
    #pragma unroll
    for (int ks = 0; ks < 16; ++ks) {
      int k0 = ks * 16 + khalf * 8;
      const float* hp = hjb + (size_t)jrow * 512 + k0;
      float4 h0 = *(const float4*)hp;
      float4 h1 = *(const float4*)(hp + 4);
      float f[8] = { h0.x, h0.y, h0.z, h0.w, h1.x, h1.y, h1.z, h1.w };
      s16x8 a;
      #pragma unroll
      for (int c = 0; c < 8; ++c)
        a[c] = (short)f2bf(fmaxf(f[c] + sm.e.hi_s[k0 + c] + sm.e.b1_s[k0 + c], 0.0f));
      #pragma unroll
      for (int nt = 0; nt < 4; ++nt) {
        s16x8 bf = *(const s16x8*)&sm.e.W2s[(nt * 32 + rsel) * 264 + k0];
        acc[nt] = __builtin_amdgcn_mfma_f32_32x32x16_bf16(a, bf, acc[nt], 0, 0, 0);
      }
    }
    float* ob = out_edge + (size_t)bi * 128 * 128;
    #pragma unroll
    for (int nt = 0; nt < 4; ++nt)
      #pragma unroll
      for (int reg = 0; reg < 16; ++reg) {
        int j = w * 32 + (reg & 3) + 8 * (reg >> 2) + 4 * khalf;
        int o = nt * 32 + rsel;
        ob[(size_t)j * 128 + o] = acc[nt][reg] + sm.e.b2_s[o];
      }
  } else {
    // ---- adjacency: row i of exp(-||ne_i - ne_j||) via LDS-tiled dots ------
    int bi = lg - 1024;                   // b*128 + i
    int b = bi >> 7;
    const float* neb = ne + (size_t)b * 128 * 256;
    int j = t & 127, kh = t >> 7;
    sm.a.nei[t] = ne[(size_t)bi * 256 + t];
    float dot = 0.0f, sqj = 0.0f, sqi = 0.0f;
    for (int tile = 0; tile < 4; ++tile) {
      __syncthreads();
      #pragma unroll
      for (int p = 0; p < 8; ++p) {
        int f = p * 256 + t;              // 0..2047 float4s
        int row = f >> 4;                 // 0..127
        int k4 = (f & 15) << 2;           // 0..60
        float4 v = *(const float4*)(neb + (size_t)row * 256 + tile * 64 + k4);
        float* dst = &sm.a.njs[row * 65 + k4];
        dst[0] = v.x; dst[1] = v.y; dst[2] = v.z; dst[3] = v.w;
      }
      __syncthreads();
      int kb = tile * 64 + kh * 32;
      #pragma unroll
      for (int k = 0; k < 32; ++k) {
        float c = sm.a.njs[j * 65 + kh * 32 + k];
        float aa = sm.a.nei[kb + k];
        dot += aa * c; sqj += c * c; sqi += aa * aa;
      }
    }
    __syncthreads();
    sm.a.red[0][t] = dot; sm.a.red[1][t] = sqj; sm.a.red[2][t] = sqi;
    __syncthreads();
    if (t < 128) {
      dot = sm.a.red[0][t] + sm.a.red[0][t + 128];
      sqj = sm.a.red[1][t] + sm.a.red[1][t + 128];
      sqi = sm.a.red[2][t] + sm.a.red[2][t + 128];
      float d2 = fmaxf(sqi + sqj - 2.0f * dot, 0.0f);
      float d = d2 > 0.0f ? sqrtf(d2) : 0.0f;
      out_adj[(size_t)bi * 128 + t] = expf(-d);
    }
  }
}

// ---------------- launch -----------------------------------------------------
extern "C" void kernel_launch(void* const* d_in, const int* in_sizes, int n_in,
                              void* d_out, int out_size, void* d_ws, size_t ws_size,
                              hipStream_t stream) {
  const float* obj    = (const float*)d_in[0];
  const float* masks  = (const float*)d_in[1];
  const float* feats  = (const float*)d_in[2];
  const float* bboxes = (const float*)d_in[3];
  const float* conf   = (const float*)d_in[4];
  const float* depth  = (const float*)d_in[5];
  const float* pose   = (const float*)d_in[6];
  const float* nw1    = (const float*)d_in[7];
  const float* nb1    = (const float*)d_in[8];
  const float* nw2    = (const float*)d_in[9];
  const float* nb2    = (const float*)d_in[10];
  const float* ew1    = (const float*)d_in[11];
  const float* eb1    = (const float*)d_in[12];
  const float* ew2    = (const float*)d_in[13];
  const float* eb2    = (const float*)d_in[14];

  char* ws = (char*)d_ws;
  // Spart: 16 * 786432 f32 = 50331648 B. h_bf / ne_bf / hihj are carved out of
  // the Spart region (Spart is dead after assemble_k runs).
  float*          Spart = (float*)ws;
  unsigned short* h_bf  = (unsigned short*)ws;                    // 1024x512 bf16 = 1 MiB
  unsigned short* ne_bf = (unsigned short*)(ws + 1048576);        // 1024x256 bf16 = 512 KiB
  float*          hihj  = (float*)(ws + 1572864);                 // 1024x512 f32 = 2 MiB
  float4*         stats = (float4*)(ws + 50331648);               // 16 KiB
  unsigned short* ni_bf = (unsigned short*)(ws + 50348032);       // 1024x1600 bf16
  unsigned short* w1b   = (unsigned short*)(ws + 53624832);       // 512x1600 bf16
  unsigned short* w2b   = (unsigned short*)(ws + 55263232);       // 256x512 bf16
  unsigned short* we1b  = (unsigned short*)(ws + 55525376);       // 512x256 bf16
  unsigned short* ew2b  = (unsigned short*)(ws + 55787520);       // 128x256 bf16
  // total used: 55853056 B (~53.3 MiB)

  float* out      = (float*)d_out;
  float* out_ne   = out;                         // 8*128*256
  float* out_edge = out + 262144;                // 8*128*128*128
  float* out_adj  = out + 262144 + 16777216;     // 8*128*128

  prep_k<<<dim3(5376), dim3(256), 0, stream>>>(masks, depth, pose, stats,
                                               nw1, nw2, ew1, ew2, w1b, w2b, we1b, ew2b);
  pooled_k<<<dim3(96, 8), dim3(256), 0, stream>>>(masks, feats, Spart);
  assemble_k<<<dim3(1024), dim3(256), 0, stream>>>(Spart, stats, obj, bboxes, conf, ni_bf);
  gemm64_k<true,  true,  1><<<dim3(8, 16), dim3(256), 0, stream>>>(ni_bf, w1b, nb1, nullptr, h_bf, NINP_, 512);
  gemm64_k<false, true,  2><<<dim3(4, 16), dim3(256), 0, stream>>>(h_bf, w2b, nb2, out_ne, ne_bf, 512, 256);
  gemm64_k<false, false, 0><<<dim3(8, 16), dim3(256), 0, stream>>>(ne_bf, we1b, nullptr, hihj, nullptr, 256, 512);
  edge_adj_k<<<dim3(2048), dim3(256), 0, stream>>>(hihj, ew2b, eb1, eb2, out_ne, out_edge, out_adj);
}

// Round 4
// 735.548 us; speedup vs baseline: 1.0217x; 1.0034x over previous
//
#include <hip/hip_runtime.h>
#include <hip/hip_bf16.h>

// Problem constants
#define B_   8
#define N_   128
#define HW_  16384
#define C_   768
#define NIN_ 1545
#define NINP_ 1600   // padded K for layer-1 GEMM (multiple of 64)
#define D1_  512
#define D_   256
#define EO_  128
#define KC_  8       // split-K factor for pooled_k (2048 k per chunk)
#define CT_  12      // channel tiles of 64

typedef short s16x8 __attribute__((ext_vector_type(8)));
typedef float f32x16 __attribute__((ext_vector_type(16)));

__device__ __forceinline__ unsigned short f2bf(float x) {
  union { __hip_bfloat16 h; unsigned short u; } cv;
  cv.h = __float2bfloat16(x);
  return cv.u;
}

// ---------------- kernel 1: fused mask stats + bf16 masks + weight convert --
// blocks [0,1024): mask stats (sum, centroid -> motion) + masks f32->bf16 copy
// blocks [1024,5376): weight f32->bf16 conversion
__global__ __launch_bounds__(256) void prep_k(const float* __restrict__ masks,
                                              const float* __restrict__ depth,
                                              const float* __restrict__ pose,
                                              float4* __restrict__ stats,
                                              unsigned short* __restrict__ masks_bf,
                                              const float* __restrict__ w1,
                                              const float* __restrict__ w2,
                                              const float* __restrict__ ew1,
                                              const float* __restrict__ ew2,
                                              unsigned short* __restrict__ w1b,
                                              unsigned short* __restrict__ w2b,
                                              unsigned short* __restrict__ we1b,
                                              unsigned short* __restrict__ ew2b) {
  if (blockIdx.x >= 1024) {
    int i = (blockIdx.x - 1024) * 256 + threadIdx.x;
    if (i < 512 * NINP_) {                       // node_w1 -> 512 x 1600 (pad 0)
      int r = i / NINP_, k = i - r * NINP_;
      w1b[i] = f2bf(k < NIN_ ? w1[r * NIN_ + k] : 0.0f);
      return;
    }
    i -= 512 * NINP_;
    if (i < 256 * 512) { w2b[i] = f2bf(w2[i]); return; }   // node_w2 256x512
    i -= 256 * 512;
    if (i < 512 * 256) {                         // [w1a; w1b] rows: 512 x 256
      int r = i >> 8, k = i & 255;
      we1b[i] = f2bf(r < 256 ? ew1[r * 512 + k] : ew1[(r - 256) * 512 + 256 + k]);
      return;
    }
    i -= 512 * 256;
    if (i < 128 * 256) { ew2b[i] = f2bf(ew2[i]); }          // edge_w2 128x256
    return;
  }
  int row = blockIdx.x;            // b*128 + n
  int b = row >> 7;
  const float4* mp = (const float4*)(masks + (size_t)row * HW_);
  unsigned short* mo = masks_bf + (size_t)row * HW_;
  double s = 0.0, sx = 0.0, sy = 0.0;
  for (int it = 0; it < 16; ++it) {
    int i4 = threadIdx.x + it * 256;
    float4 v = mp[i4];
    // bf16 copy for pooled_k (identical rounding to previous in-kernel cvt)
    ushort4 pv = { f2bf(v.x), f2bf(v.y), f2bf(v.z), f2bf(v.w) };
    *(ushort4*)(mo + i4 * 4) = pv;
    int flat = i4 * 4;
    int y = flat >> 7, xb = flat & 127;
    double rs = (double)v.x + (double)v.y + (double)v.z + (double)v.w;
    s += rs;
    sx += (double)v.x * xb + (double)v.y * (xb + 1) + (double)v.z * (xb + 2) + (double)v.w * (xb + 3);
    sy += rs * (double)y;
  }
  for (int off = 32; off; off >>= 1) {
    s  += __shfl_down(s,  off);
    sx += __shfl_down(sx, off);
    sy += __shfl_down(sy, off);
  }
  __shared__ double red[3][4];
  int w = threadIdx.x >> 6, l = threadIdx.x & 63;
  if (l == 0) { red[0][w] = s; red[1][w] = sx; red[2][w] = sy; }
  __syncthreads();
  if (threadIdx.x == 0) {
    s  = red[0][0] + red[0][1] + red[0][2] + red[0][3];
    sx = red[1][0] + red[1][1] + red[1][2] + red[1][3];
    sy = red[2][0] + red[2][1] + red[2][2] + red[2][3];
    double msum = s + 1e-6;
    double cx = sx / msum, cy = sy / msum;
    int cxi = (int)rint(cx); cxi = min(127, max(0, cxi));
    int cyi = (int)rint(cy); cyi = min(127, max(0, cyi));
    double z = (double)depth[(size_t)b * HW_ + cyi * 128 + cxi];
    // K = I3: X = cx*z, Y = cy*z
    double Ph[4] = { cx * z, cy * z, z, 1.0 };
    const float* P = pose + b * 16;
    double pn[4];
    #pragma unroll
    for (int r = 0; r < 4; ++r)
      pn[r] = (double)P[r*4+0]*Ph[0] + (double)P[r*4+1]*Ph[1] + (double)P[r*4+2]*Ph[2] + (double)P[r*4+3]*Ph[3];
    double inv3 = 1.0 / pn[3];
    stats[row] = make_float4((float)(1.0 / msum), (float)(pn[0]*inv3), (float)(pn[1]*inv3), (float)(pn[2]*inv3));
  }
}

// ---------------- kernel 2: pooled = masks @ feats^T (split-K, bf16 MFMA) ---
// grid 768: id -> b (8) x ct (12 channel tiles of 64) x kc (8 K-chunks of 2048).
// A = masks_bf (bf16, direct 16B LDS staging, no cvt); B = feats f32 (cvt).
// masks is LLC-resident (67 MB) so the 12x ct re-read is cheap; feats read once.
__global__ __launch_bounds__(256) void pooled_k(const unsigned short* __restrict__ masks_bf,
                                                const float* __restrict__ feats,
                                                float* __restrict__ Spart) {
  __shared__ short As[128 * 72];
  __shared__ short Bs[64 * 72];
  int id = blockIdx.x;                          // 0..767
  int b  = id / 96;
  int lx = id - b * 96;
  int ct = lx % 12, kc = lx / 12;               // kc in [0,8): K-chunk of 2048
  const unsigned short* mb = masks_bf + (size_t)b * N_ * HW_;
  const float* fb = feats + ((size_t)b * C_ + (size_t)ct * 64) * HW_;
  int t = threadIdx.x, w = t >> 6, l = t & 63;
  int rsel = l & 31, khalf = l >> 5;
  f32x16 acc[2];
  #pragma unroll
  for (int nt = 0; nt < 2; ++nt)
    #pragma unroll
    for (int i = 0; i < 16; ++i) acc[nt][i] = 0.0f;

  for (int kt = 0; kt < 32; ++kt) {
    int kbase = kc * 2048 + kt * 64;
    // A: 128 rows x 64 k bf16 = 16 KB -> 4 x 16B per thread, no conversion
    #pragma unroll
    for (int c = 0; c < 4; ++c) {
      int chunk = t + 256 * c;           // 0..1023
      int row = chunk >> 3;              // 0..127
      int kof = (chunk & 7) * 8;         // 0..56 (bf16 elems)
      *(uint4*)((unsigned short*)As + row * 72 + kof) =
          *(const uint4*)(mb + (size_t)row * HW_ + kbase + kof);
    }
    // B: 64 rows x 64 k f32 -> cvt -> 4 x ushort4 per thread
    #pragma unroll
    for (int c = 0; c < 4; ++c) {
      int chunk = t + 256 * c;           // 0..1023
      int row = chunk >> 4;              // 0..63
      int kof = (chunk & 15) << 2;       // 0..60
      float4 vb = *(const float4*)(fb + (size_t)row * HW_ + kbase + kof);
      ushort4 pb = { f2bf(vb.x), f2bf(vb.y), f2bf(vb.z), f2bf(vb.w) };
      *(ushort4*)((unsigned short*)Bs + row * 72 + kof) = pb;
    }
    __syncthreads();
    #pragma unroll
    for (int ks = 0; ks < 4; ++ks) {
      s16x8 a = *(const s16x8*)&As[(w * 32 + rsel) * 72 + ks * 16 + khalf * 8];
      #pragma unroll
      for (int nt = 0; nt < 2; ++nt) {
        s16x8 bf = *(const s16x8*)&Bs[(nt * 32 + rsel) * 72 + ks * 16 + khalf * 8];
        acc[nt] = __builtin_amdgcn_mfma_f32_32x32x16_bf16(a, bf, acc[nt], 0, 0, 0);
      }
    }
    __syncthreads();
  }
  float* op = Spart + (size_t)kc * 786432 + (size_t)b * 98304;
  #pragma unroll
  for (int nt = 0; nt < 2; ++nt)
    #pragma unroll
    for (int reg = 0; reg < 16; ++reg) {
      int rm = w * 32 + (reg & 3) + 8 * (reg >> 2) + 4 * khalf;
      int cn = ct * 64 + nt * 32 + rsel;
      op[rm * C_ + cn] = acc[nt][reg];
    }
}

// ---------------- kernel 3a: reduce split-K partials + assemble node_input --
__global__ __launch_bounds__(256) void assemble_k(const float* __restrict__ Spart,
                                                  const float4* __restrict__ stats,
                                                  const float* __restrict__ obj,
                                                  const float* __restrict__ bboxes,
                                                  const float* __restrict__ conf,
                                                  unsigned short* __restrict__ ni) {
  int r = blockIdx.x;
  float4 st = stats[r];
  float x1 = bboxes[r*4+0], y1 = bboxes[r*4+1], x2 = bboxes[r*4+2], y2 = bboxes[r*4+3];
  for (int k = threadIdx.x; k < NINP_; k += 256) {
    float v;
    if (k < 768) {
      float acc = 0.0f;
      #pragma unroll
      for (int kc = 0; kc < KC_; ++kc) acc += Spart[(size_t)kc * 786432 + (size_t)r * C_ + k];
      v = acc * st.x;
    } else if (k < 1537) v = obj[(size_t)r * 769 + (k - 768)];
    else if (k == 1537) v = 0.5f * (x1 + x2);
    else if (k == 1538) v = 0.5f * (y1 + y2);
    else if (k == 1539) v = x2 - x1;
    else if (k == 1540) v = y2 - y1;
    else if (k == 1541) v = conf[r];
    else if (k == 1542) v = st.y;
    else if (k == 1543) v = st.z;
    else if (k == 1544) v = st.w;
    else v = 0.0f;
    ni[(size_t)r * NINP_ + k] = f2bf(v);
  }
}

// ---------------- generic 64x64 bf16 GEMM: C[m,n] = act(bias + A·B^T) -------
// A: M x K bf16 (row-major, stride K), B: N x K bf16. K multiple of 64.
template <bool RELU, bool BIAS, int OUTM>  // OUTM: 0 f32, 1 bf16, 2 both
__global__ __launch_bounds__(256) void gemm64_k(const unsigned short* __restrict__ A,
                                                const unsigned short* __restrict__ Bm,
                                                const float* __restrict__ bias,
                                                float* __restrict__ Cf,
                                                unsigned short* __restrict__ Cb,
                                                int K, int N) {
  __shared__ short As[64 * 72];
  __shared__ short Bs[64 * 72];
  int n0 = blockIdx.x * 64, m0 = blockIdx.y * 64;
  int t = threadIdx.x, w = t >> 6, l = t & 63;
  int rsel = l & 31, khalf = l >> 5;
  int mh = (w & 1) * 32, nh = (w >> 1) * 32;
  f32x16 acc;
  #pragma unroll
  for (int i = 0; i < 16; ++i) acc[i] = 0.0f;

  for (int k0 = 0; k0 < K; k0 += 64) {
    #pragma unroll
    for (int c = 0; c < 2; ++c) {
      int chunk = t + 256 * c;            // 0..511
      int row = chunk >> 3, kof = (chunk & 7) * 8;
      *(uint4*)((unsigned short*)As + row * 72 + kof) =
          *(const uint4*)&A[(size_t)(m0 + row) * K + k0 + kof];
      *(uint4*)((unsigned short*)Bs + row * 72 + kof) =
          *(const uint4*)&Bm[(size_t)(n0 + row) * K + k0 + kof];
    }
    __syncthreads();
    #pragma unroll
    for (int ks = 0; ks < 4; ++ks) {
      s16x8 a = *(const s16x8*)&As[(mh + rsel) * 72 + ks * 16 + khalf * 8];
      s16x8 bf = *(const s16x8*)&Bs[(nh + rsel) * 72 + ks * 16 + khalf * 8];
      acc = __builtin_amdgcn_mfma_f32_32x32x16_bf16(a, bf, acc, 0, 0, 0);
    }
    __syncthreads();
  }
  #pragma unroll
  for (int reg = 0; reg < 16; ++reg) {
    int rm = m0 + mh + (reg & 3) + 8 * (reg >> 2) + 4 * khalf;
    int cn = n0 + nh + rsel;
    float v = acc[reg];
    if (BIAS) v += bias[cn];
    if (RELU) v = fmaxf(v, 0.0f);
    if (OUTM == 0 || OUTM == 2) Cf[(size_t)rm * N + cn] = v;
    if (OUTM == 1 || OUTM == 2) Cb[(size_t)rm * N + cn] = f2bf(v);
  }
}

// ---------------- kernel 4: fused edge MLP + adjacency ----------------------
// grid 2048 with XCD-grouping swizzle; lg < 1024: edge MLP for (b,i),
// lg >= 1024: adjacency row (b,i) via coalesced LDS-tiled dot products.
__global__ __launch_bounds__(256) void edge_adj_k(const float* __restrict__ hihj,
                                                  const unsigned short* __restrict__ ew2b,
                                                  const float* __restrict__ eb1,
                                                  const float* __restrict__ eb2,
                                                  const float* __restrict__ ne,
                                                  float* __restrict__ out_edge,
                                                  float* __restrict__ out_adj) {
  __shared__ union {
    struct { short W2s[128 * 264]; float hi_s[256]; float b1_s[256]; float b2_s[128]; } e;
    struct { float njs[128 * 65]; float nei[256]; float red[3][256]; } a;
  } sm;
  int id = blockIdx.x;                    // 0..2047
  int lg = (id & 7) * 256 + (id >> 3);    // bijective: 2048 % 8 == 0
  int t = threadIdx.x;

  if (lg < 1024) {
    // ---- edge MLP: he[j,k]=relu(hi[i,k]+hj[j,k]+b1[k]) in-reg, GEMM vs w2 --
    int bi = lg;                          // b*128 + i
    int b = bi >> 7;
    int w = t >> 6, l = t & 63;
    int rsel = l & 31, khalf = l >> 5;

    #pragma unroll
    for (int c = 0; c < 16; ++c) {
      int chunk = t + 256 * c;            // 0..4095
      int row = chunk >> 5, kof = (chunk & 31) * 8;
      *(uint4*)((unsigned short*)sm.e.W2s + row * 264 + kof) = *(const uint4*)&ew2b[row * 256 + kof];
    }
    sm.e.hi_s[t] = hihj[(size_t)bi * 512 + t];    // hi of node i
    sm.e.b1_s[t] = eb1[t];
    if (t < 128) sm.e.b2_s[t] = eb2[t];
    __syncthreads();

    f32x16 acc[4];
    #pragma unroll
    for (int nt = 0; nt < 4; ++nt)
      #pragma unroll
      for (int i = 0; i < 16; ++i) acc[nt][i] = 0.0f;

    const float* hjb = hihj + (size_t)b * 128 * 512 + 256;
    int jrow = w * 32 + rsel;
    #pragma unroll
    for (int ks = 0; ks < 16; ++ks) {
      int k0 = ks * 16 + khalf * 8;
      const float* hp = hjb + (size_t)jrow * 512 + k0;
      float4 h0 = *(const float4*)hp;
      float4 h1 = *(const float4*)(hp + 4);
      float f[8] = { h0.x, h0.y, h0.z, h0.w, h1.x, h1.y, h1.z, h1.w };
      s16x8 a;
      #pragma unroll
      for (int c = 0; c < 8; ++c)
        a[c] = (short)f2bf(fmaxf(f[c] + sm.e.hi_s[k0 + c] + sm.e.b1_s[k0 + c], 0.0f));
      #pragma unroll
      for (int nt = 0; nt < 4; ++nt) {
        s16x8 bf = *(const s16x8*)&sm.e.W2s[(nt * 32 + rsel) * 264 + k0];
        acc[nt] = __builtin_amdgcn_mfma_f32_32x32x16_bf16(a, bf, acc[nt], 0, 0, 0);
      }
    }
    float* ob = out_edge + (size_t)bi * 128 * 128;
    #pragma unroll
    for (int nt = 0; nt < 4; ++nt)
      #pragma unroll
      for (int reg = 0; reg < 16; ++reg) {
        int j = w * 32 + (reg & 3) + 8 * (reg >> 2) + 4 * khalf;
        int o = nt * 32 + rsel;
        ob[(size_t)j * 128 + o] = acc[nt][reg] + sm.e.b2_s[o];
      }
  } else {
    // ---- adjacency: row i of exp(-||ne_i - ne_j||) via LDS-tiled dots ------
    int bi = lg - 1024;                   // b*128 + i
    int b = bi >> 7;
    const float* neb = ne + (size_t)b * 128 * 256;
    int j = t & 127, kh = t >> 7;
    sm.a.nei[t] = ne[(size_t)bi * 256 + t];
    float dot = 0.0f, sqj = 0.0f, sqi = 0.0f;
    for (int tile = 0; tile < 4; ++tile) {
      __syncthreads();
      #pragma unroll
      for (int p = 0; p < 8; ++p) {
        int f = p * 256 + t;              // 0..2047 float4s
        int row = f >> 4;                 // 0..127
        int k4 = (f & 15) << 2;           // 0..60
        float4 v = *(const float4*)(neb + (size_t)row * 256 + tile * 64 + k4);
        float* dst = &sm.a.njs[row * 65 + k4];
        dst[0] = v.x; dst[1] = v.y; dst[2] = v.z; dst[3] = v.w;
      }
      __syncthreads();
      int kb = tile * 64 + kh * 32;
      #pragma unroll
      for (int k = 0; k < 32; ++k) {
        float c = sm.a.njs[j * 65 + kh * 32 + k];
        float aa = sm.a.nei[kb + k];
        dot += aa * c; sqj += c * c; sqi += aa * aa;
      }
    }
    __syncthreads();
    sm.a.red[0][t] = dot; sm.a.red[1][t] = sqj; sm.a.red[2][t] = sqi;
    __syncthreads();
    if (t < 128) {
      dot = sm.a.red[0][t] + sm.a.red[0][t + 128];
      sqj = sm.a.red[1][t] + sm.a.red[1][t + 128];
      sqi = sm.a.red[2][t] + sm.a.red[2][t + 128];
      float d2 = fmaxf(sqi + sqj - 2.0f * dot, 0.0f);
      float d = d2 > 0.0f ? sqrtf(d2) : 0.0f;
      out_adj[(size_t)bi * 128 + t] = expf(-d);
    }
  }
}

// ---------------- launch -----------------------------------------------------
extern "C" void kernel_launch(void* const* d_in, const int* in_sizes, int n_in,
                              void* d_out, int out_size, void* d_ws, size_t ws_size,
                              hipStream_t stream) {
  const float* obj    = (const float*)d_in[0];
  const float* masks  = (const float*)d_in[1];
  const float* feats  = (const float*)d_in[2];
  const float* bboxes = (const float*)d_in[3];
  const float* conf   = (const float*)d_in[4];
  const float* depth  = (const float*)d_in[5];
  const float* pose   = (const float*)d_in[6];
  const float* nw1    = (const float*)d_in[7];
  const float* nb1    = (const float*)d_in[8];
  const float* nw2    = (const float*)d_in[9];
  const float* nb2    = (const float*)d_in[10];
  const float* ew1    = (const float*)d_in[11];
  const float* eb1    = (const float*)d_in[12];
  const float* ew2    = (const float*)d_in[13];
  const float* eb2    = (const float*)d_in[14];

  char* ws = (char*)d_ws;
  // Spart: 8 * 786432 f32 = 25165824 B. h_bf / ne_bf / hihj are carved out of
  // the Spart region (Spart is dead after assemble_k runs).
  float*          Spart = (float*)ws;
  unsigned short* h_bf  = (unsigned short*)ws;                    // 1024x512 bf16 = 1 MiB
  unsigned short* ne_bf = (unsigned short*)(ws + 1048576);        // 1024x256 bf16 = 512 KiB
  float*          hihj  = (float*)(ws + 1572864);                 // 1024x512 f32 = 2 MiB
  float4*         stats = (float4*)(ws + 25165824);               // 16 KiB
  unsigned short* ni_bf = (unsigned short*)(ws + 25182208);       // 1024x1600 bf16 -> ends 28459008
  unsigned short* w1b   = (unsigned short*)(ws + 28459008);       // 512x1600 bf16 -> 30097408
  unsigned short* w2b   = (unsigned short*)(ws + 30097408);       // 256x512 bf16 -> 30359552
  unsigned short* we1b  = (unsigned short*)(ws + 30359552);       // 512x256 bf16 -> 30621696
  unsigned short* ew2b  = (unsigned short*)(ws + 30621696);       // 128x256 bf16 -> 30687232
  unsigned short* mkbf  = (unsigned short*)(ws + 30687232);       // masks bf16 32 MiB -> 64241664
  // total used: ~61.3 MiB

  float* out      = (float*)d_out;
  float* out_ne   = out;                         // 8*128*256
  float* out_edge = out + 262144;                // 8*128*128*128
  float* out_adj  = out + 262144 + 16777216;     // 8*128*128

  prep_k<<<dim3(5376), dim3(256), 0, stream>>>(masks, depth, pose, stats, mkbf,
                                               nw1, nw2, ew1, ew2, w1b, w2b, we1b, ew2b);
  pooled_k<<<dim3(768), dim3(256), 0, stream>>>(mkbf, feats, Spart);
  assemble_k<<<dim3(1024), dim3(256), 0, stream>>>(Spart, stats, obj, bboxes, conf, ni_bf);
  gemm64_k<true,  true,  1><<<dim3(8, 16), dim3(256), 0, stream>>>(ni_bf, w1b, nb1, nullptr, h_bf, NINP_, 512);
  gemm64_k<false, true,  2><<<dim3(4, 16), dim3(256), 0, stream>>>(h_bf, w2b, nb2, out_ne, ne_bf, 512, 256);
  gemm64_k<false, false, 0><<<dim3(8, 16), dim3(256), 0, stream>>>(ne_bf, we1b, nullptr, hihj, nullptr, 256, 512);
  edge_adj_k<<<dim3(2048), dim3(256), 0, stream>>>(hihj, ew2b, eb1, eb2, out_ne, out_edge, out_adj);
}